// Round 4
// baseline (677.741 us; speedup 1.0000x reference)
//
#include <hip/hip_runtime.h>
#include <hip/hip_bf16.h>
#include <hip/hip_cooperative_groups.h>

namespace cg = cooperative_groups;

#define NN 32
#define LL 4096
#define EE 512
#define HH 8
#define DD 64
#define FF 2048
#define CC 8            // fallback path: row chunks per head-block

// ===========================================================================
// PATH 1: single cooperative kernel, 1024 blocks x 256 threads.
// ===========================================================================
__global__ __launch_bounds__(256, 4) void k_mega(
    const float* __restrict__ Cp, const float* __restrict__ W1,
    const float* __restrict__ W3, const float* __restrict__ Wf1,
    const float* __restrict__ bf1, const float* __restrict__ Wf2,
    const float* __restrict__ bf2, const float* __restrict__ gamma,
    const float* __restrict__ beta, float* __restrict__ out,
    float* __restrict__ ws)
{
    cg::grid_group grid = cg::this_grid();
    __shared__ float lds[EE + 256];     // 3 KB

    float* P   = ws;                    // 32*8*4*512 = 524288 floats
    float* V   = P + 524288;
    float* phi = V + DD * EE;
    float* w3  = phi + NN * EE;
    float* h1  = w3 + NN * EE;
    float* x   = h1 + NN * FF;

    const int b    = blockIdx.x;
    const int t    = threadIdx.x;
    const int lane = t & 63;
    const int wwid = (b << 2) | (t >> 6);

    // Phase A: Cp row-block partial sums (+ W1 colsums on blocks 0..31)
    {
        int n    = b >> 5;
        int sub  = b & 31;
        int h    = sub >> 2;
        int q    = sub & 3;
        int e4   = t & 127;
        int half = t >> 7;
        const float4* base = reinterpret_cast<const float4*>(Cp) +
            (size_t)(n * LL + sub * 128 + half) * (EE / 4) + e4;
        float ax = 0.f, ay = 0.f, az = 0.f, aw = 0.f;
#pragma unroll 8
        for (int r = 0; r < 64; ++r) {
            float4 v = base[(size_t)r * 2 * (EE / 4)];
            ax += v.x; ay += v.y; az += v.z; aw += v.w;
        }
        float4* sh = reinterpret_cast<float4*>(lds);
        if (half) { float4 o; o.x = ax; o.y = ay; o.z = az; o.w = aw; sh[e4] = o; }
        __syncthreads();
        if (!half) {
            float4 o = sh[e4];
            o.x += ax; o.y += ay; o.z += az; o.w += aw;
            reinterpret_cast<float4*>(P + (size_t)((n * HH + h) * 4 + q) * EE)[e4] = o;
        }
        if (b < 32) {
            int idx = b * 256 + t;
            int d = idx >> 7, ee4 = idx & 127;
            float vx = 0.f, vy = 0.f, vz = 0.f, vw = 0.f;
#pragma unroll
            for (int j = 0; j < 8; ++j) {
                float4 v = reinterpret_cast<const float4*>(
                    W1 + (size_t)(j * 64 + d) * EE)[ee4];
                vx += v.x; vy += v.y; vz += v.z; vw += v.w;
            }
            float4 o; o.x = vx; o.y = vy; o.z = vz; o.w = vw;
            reinterpret_cast<float4*>(V + (size_t)d * EE)[ee4] = o;
        }
    }
    grid.sync();

    // Phase B: phi
    if (b < 256) {
        int n = b >> 3, h = b & 7;
        float* S   = lds;
        float* red = lds + EE;
#pragma unroll
        for (int rep = 0; rep < 2; ++rep) {
            int e = t + rep * 256;
            float s = 0.f;
#pragma unroll
            for (int q = 0; q < 4; ++q)
                s += P[(size_t)((n * HH + h) * 4 + q) * EE + e];
            S[e] = s;
        }
        __syncthreads();
        int d = t >> 2, ch = t & 3;
        const float* Vr = V + (size_t)d * EE + ch * 128;
        const float* Sr = S + ch * 128;
        float acc = 0.f;
#pragma unroll 4
        for (int e = 0; e < 128; ++e) acc += Sr[e] * Vr[e];
        red[t] = acc;
        __syncthreads();
        if (t < DD)
            phi[(size_t)n * EE + h * DD + t] =
                red[t * 4] + red[t * 4 + 1] + red[t * 4 + 2] + red[t * 4 + 3];
    }
    grid.sync();

    // Phase C: w3 = phi @ W3^T
    {
        int f = wwid >> 3, ng = wwid & 7, n0 = ng * 4;
        float acc[4] = {0.f, 0.f, 0.f, 0.f};
#pragma unroll
        for (int k = 0; k < 2; ++k) {
            float4 w4 = reinterpret_cast<const float4*>(W3 + (size_t)f * EE)[k * 64 + lane];
#pragma unroll
            for (int g = 0; g < 4; ++g) {
                float4 a4 = reinterpret_cast<const float4*>(
                    phi + (size_t)(n0 + g) * EE)[k * 64 + lane];
                acc[g] += a4.x * w4.x + a4.y * w4.y + a4.z * w4.z + a4.w * w4.w;
            }
        }
#pragma unroll
        for (int g = 0; g < 4; ++g) {
            float s = acc[g];
#pragma unroll
            for (int m = 32; m; m >>= 1) s += __shfl_xor(s, m);
            if (lane == 0) w3[(size_t)(n0 + g) * EE + f] = s;
        }
    }
    grid.sync();

    // Phase D: h1 = relu(w3 @ Wf1^T + bf1)
    {
        int f0 = (wwid >> 2) * 2, ng = wwid & 3, n0 = ng * 8;
        float acc[8][2] = {};
#pragma unroll
        for (int fi = 0; fi < 2; ++fi) {
#pragma unroll
            for (int k = 0; k < 2; ++k) {
                float4 w4 = reinterpret_cast<const float4*>(
                    Wf1 + (size_t)(f0 + fi) * EE)[k * 64 + lane];
#pragma unroll
                for (int g = 0; g < 8; ++g) {
                    float4 a4 = reinterpret_cast<const float4*>(
                        w3 + (size_t)(n0 + g) * EE)[k * 64 + lane];
                    acc[g][fi] += a4.x * w4.x + a4.y * w4.y + a4.z * w4.z + a4.w * w4.w;
                }
            }
        }
#pragma unroll
        for (int fi = 0; fi < 2; ++fi) {
#pragma unroll
            for (int g = 0; g < 8; ++g) {
                float s = acc[g][fi];
#pragma unroll
                for (int m = 32; m; m >>= 1) s += __shfl_xor(s, m);
                if (lane == 0)
                    h1[(size_t)(n0 + g) * FF + f0 + fi] = fmaxf(s + bf1[f0 + fi], 0.f);
            }
        }
    }
    grid.sync();

    // Phase E: x = h1 @ Wf2^T + bf2 + w3
    {
        int f = wwid >> 3, ng = wwid & 7, n0 = ng * 4;
        float acc[4] = {0.f, 0.f, 0.f, 0.f};
#pragma unroll
        for (int k = 0; k < 8; ++k) {
            float4 w4 = reinterpret_cast<const float4*>(Wf2 + (size_t)f * FF)[k * 64 + lane];
#pragma unroll
            for (int g = 0; g < 4; ++g) {
                float4 a4 = reinterpret_cast<const float4*>(
                    h1 + (size_t)(n0 + g) * FF)[k * 64 + lane];
                acc[g] += a4.x * w4.x + a4.y * w4.y + a4.z * w4.z + a4.w * w4.w;
            }
        }
#pragma unroll
        for (int g = 0; g < 4; ++g) {
            float s = acc[g];
#pragma unroll
            for (int m = 32; m; m >>= 1) s += __shfl_xor(s, m);
            if (lane == 0)
                x[(size_t)(n0 + g) * EE + f] =
                    s + bf2[f] + w3[(size_t)(n0 + g) * EE + f];
        }
    }
    grid.sync();

    // Phase F: LayerNorm
    if (b < NN) {
        float* wred = lds;
        int n = b;
        float a0 = x[(size_t)n * EE + t];
        float b0 = x[(size_t)n * EE + 256 + t];
        float s = a0 + b0;
#pragma unroll
        for (int off = 32; off > 0; off >>= 1) s += __shfl_down(s, off);
        int wid = t >> 6;
        if ((t & 63) == 0) wred[wid] = s;
        __syncthreads();
        if (t == 0) wred[0] = (wred[0] + wred[1] + wred[2] + wred[3]) * (1.0f / EE);
        __syncthreads();
        float mu = wred[0];
        float da = a0 - mu, db = b0 - mu;
        float q = da * da + db * db;
#pragma unroll
        for (int off = 32; off > 0; off >>= 1) q += __shfl_down(q, off);
        __syncthreads();
        if ((t & 63) == 0) wred[wid] = q;
        __syncthreads();
        if (t == 0) wred[0] = (wred[0] + wred[1] + wred[2] + wred[3]) * (1.0f / EE);
        __syncthreads();
        float var = wred[0];
        float rstd = rsqrtf(var + 1e-5f);
        out[(size_t)n * EE + t]       = da * rstd * gamma[t] + beta[t];
        out[(size_t)n * EE + 256 + t] = db * rstd * gamma[t + 256] + beta[t + 256];
    }
}

// ===========================================================================
// PATH 2 (fallback): the verified R2 six-kernel pipeline.
// ===========================================================================
__global__ void k_prep(const float* __restrict__ Cp, const float* __restrict__ W1,
                       float* __restrict__ P, float* __restrict__ V) {
    int bid = blockIdx.x;
    int tid = threadIdx.x;
    if (bid < 2048) {
        int c = bid & 7;
        int h = (bid >> 3) & 7;
        int n = bid >> 6;
        const float4* base = reinterpret_cast<const float4*>(
            Cp + ((size_t)n * LL + (size_t)h * 512 + (size_t)c * 64) * EE) + tid;
        float ax = 0.f, ay = 0.f, az = 0.f, aw = 0.f;
#pragma unroll 8
        for (int r = 0; r < 64; ++r) {
            float4 v = base[(size_t)r * (EE / 4)];
            ax += v.x; ay += v.y; az += v.z; aw += v.w;
        }
        float4 o; o.x = ax; o.y = ay; o.z = az; o.w = aw;
        reinterpret_cast<float4*>(P + (((size_t)c * NN + bid / 64) * HH + h) * EE)[tid] = o;
    } else {
        int gid2 = (bid - 2048) * 128 + tid;
#pragma unroll
        for (int rep = 0; rep < 2; ++rep) {
            int idx = gid2 + rep * 4096;
            int d = idx >> 7;
            int e4 = idx & 127;
            float ax = 0.f, ay = 0.f, az = 0.f, aw = 0.f;
#pragma unroll
            for (int j = 0; j < 8; ++j) {
                float4 v = reinterpret_cast<const float4*>(
                    W1 + (size_t)(j * 64 + d) * EE)[e4];
                ax += v.x; ay += v.y; az += v.z; aw += v.w;
            }
            float4 o; o.x = ax; o.y = ay; o.z = az; o.w = aw;
            reinterpret_cast<float4*>(V + (size_t)d * EE)[e4] = o;
        }
    }
}

__global__ void k_phi(const float* __restrict__ P, const float* __restrict__ V,
                      float* __restrict__ phi) {
    __shared__ float S[EE];
    __shared__ float red[256];
    int n = blockIdx.x >> 3;
    int h = blockIdx.x & 7;
    for (int e = threadIdx.x; e < EE; e += 256) {
        float s = 0.f;
#pragma unroll
        for (int c = 0; c < CC; ++c)
            s += P[(((size_t)c * NN + n) * HH + h) * EE + e];
        S[e] = s;
    }
    __syncthreads();
    int d  = threadIdx.x >> 2;
    int ch = threadIdx.x & 3;
    const float* Vr = V + (size_t)d * EE + ch * 128;
    const float* Sr = S + ch * 128;
    float acc = 0.f;
#pragma unroll 4
    for (int e = 0; e < 128; ++e) acc += Sr[e] * Vr[e];
    red[threadIdx.x] = acc;
    __syncthreads();
    if (threadIdx.x < DD) {
        int dd = threadIdx.x;
        float r = red[dd * 4] + red[dd * 4 + 1] + red[dd * 4 + 2] + red[dd * 4 + 3];
        phi[(size_t)n * EE + h * DD + dd] = r;
    }
}

template<int K, int F, int NG, int FPW, int MODE>
__global__ __launch_bounds__(256) void k_gemm(const float* __restrict__ A,
                                              const float* __restrict__ W,
                                              const float* __restrict__ bias,
                                              const float* __restrict__ res,
                                              float* __restrict__ out) {
    constexpr int V4 = K / 256;
    int wid  = (blockIdx.x * 256 + threadIdx.x) >> 6;
    int lane = threadIdx.x & 63;
    constexpr int NGROUPS = NN / NG;
    int ng = wid % NGROUPS;
    int fc = wid / NGROUPS;
    int n0 = ng * NG;
    int f0 = fc * FPW;

    float4 a4[NG][V4];
#pragma unroll
    for (int g = 0; g < NG; ++g)
#pragma unroll
        for (int k = 0; k < V4; ++k)
            a4[g][k] = reinterpret_cast<const float4*>(
                A + (size_t)(n0 + g) * K)[k * 64 + lane];

#pragma unroll
    for (int fi = 0; fi < FPW; ++fi) {
        int f = f0 + fi;
        float4 w4[V4];
#pragma unroll
        for (int k = 0; k < V4; ++k)
            w4[k] = reinterpret_cast<const float4*>(
                W + (size_t)f * K)[k * 64 + lane];
        float acc[NG];
#pragma unroll
        for (int g = 0; g < NG; ++g) {
            float s = 0.f;
#pragma unroll
            for (int k = 0; k < V4; ++k) {
                s += a4[g][k].x * w4[k].x + a4[g][k].y * w4[k].y
                   + a4[g][k].z * w4[k].z + a4[g][k].w * w4[k].w;
            }
#pragma unroll
            for (int m = 32; m > 0; m >>= 1) s += __shfl_xor(s, m);
            acc[g] = s;
        }
        if (lane == 0) {
            float b = (MODE == 0) ? 0.f : bias[f];
#pragma unroll
            for (int g = 0; g < NG; ++g) {
                float v = acc[g] + b;
                if (MODE == 1) v = fmaxf(v, 0.f);
                if (MODE == 2) v += res[(size_t)(n0 + g) * F + f];
                out[(size_t)(n0 + g) * F + f] = v;
            }
        }
    }
}

__global__ void k_ln(const float* __restrict__ x, const float* __restrict__ gamma,
                     const float* __restrict__ beta, float* __restrict__ out) {
    __shared__ float wred[4];
    int n = blockIdx.x;
    int tid = threadIdx.x;
    float a = x[(size_t)n * EE + tid];
    float b = x[(size_t)n * EE + 256 + tid];
    float s = a + b;
#pragma unroll
    for (int off = 32; off > 0; off >>= 1) s += __shfl_down(s, off);
    int wid = tid >> 6;
    if ((tid & 63) == 0) wred[wid] = s;
    __syncthreads();
    if (tid == 0) wred[0] = (wred[0] + wred[1] + wred[2] + wred[3]) * (1.0f / EE);
    __syncthreads();
    float mu = wred[0];
    float da = a - mu, db = b - mu;
    float q = da * da + db * db;
#pragma unroll
    for (int off = 32; off > 0; off >>= 1) q += __shfl_down(q, off);
    __syncthreads();
    if ((tid & 63) == 0) wred[wid] = q;
    __syncthreads();
    if (tid == 0) wred[0] = (wred[0] + wred[1] + wred[2] + wred[3]) * (1.0f / EE);
    __syncthreads();
    float var = wred[0];
    float rstd = rsqrtf(var + 1e-5f);
    out[(size_t)n * EE + tid]       = da * rstd * gamma[tid] + beta[tid];
    out[(size_t)n * EE + 256 + tid] = db * rstd * gamma[tid + 256] + beta[tid + 256];
}

// ===========================================================================
extern "C" void kernel_launch(void* const* d_in, const int* in_sizes, int n_in,
                              void* d_out, int out_size, void* d_ws, size_t ws_size,
                              hipStream_t stream) {
    const float* Cp    = (const float*)d_in[0];
    const float* W1    = (const float*)d_in[1];
    // d_in[2] = W2: unused — softmax over a size-1 axis is identically 1.
    const float* W3    = (const float*)d_in[3];
    const float* Wf1   = (const float*)d_in[4];
    const float* bf1   = (const float*)d_in[5];
    const float* Wf2   = (const float*)d_in[6];
    const float* bf2   = (const float*)d_in[7];
    const float* gamma = (const float*)d_in[8];
    const float* beta  = (const float*)d_in[9];
    float* out = (float*)d_out;
    float* ws  = (float*)d_ws;

    // Attempt PATH 1: single cooperative dispatch.
    void* args[] = {
        (void*)&Cp, (void*)&W1, (void*)&W3, (void*)&Wf1, (void*)&bf1,
        (void*)&Wf2, (void*)&bf2, (void*)&gamma, (void*)&beta,
        (void*)&out, (void*)&ws,
    };
    hipError_t err = hipLaunchCooperativeKernel((void*)k_mega, dim3(1024),
                                                dim3(256), args, 0, stream);
    if (err == hipSuccess) return;

    // PATH 2 fallback: verified six-kernel pipeline (deterministic: the
    // cooperative-launch error is a static property of binary+device).
    float* P   = ws;                              // 8*32*8*512 floats
    float* V   = P + (size_t)CC * NN * HH * EE;
    float* phi = V + (size_t)DD * EE;
    float* w3  = phi + (size_t)NN * EE;
    float* h1  = w3 + (size_t)NN * EE;
    float* x   = h1 + (size_t)NN * FF;

    k_prep<<<2048 + 32, 128, 0, stream>>>(Cp, W1, P, V);
    k_phi<<<NN * HH, 256, 0, stream>>>(P, V, phi);
    k_gemm<EE, EE, 8, 2, 0><<<256, 256, 0, stream>>>(phi, W3, nullptr, nullptr, w3);
    k_gemm<EE, FF, 8, 2, 1><<<1024, 256, 0, stream>>>(w3, Wf1, bf1, nullptr, h1);
    k_gemm<FF, EE, 4, 1, 2><<<1024, 256, 0, stream>>>(h1, Wf2, bf2, w3, x);
    k_ln<<<NN, 256, 0, stream>>>(x, gamma, beta, out);
}

// Round 5
// 102.321 us; speedup vs baseline: 6.6237x; 6.6237x over previous
//
#include <hip/hip_runtime.h>
#include <hip/hip_bf16.h>

#define NN 32
#define LL 4096
#define EE 512
#define HH 8
#define DD 64
#define FF 2048

typedef float f32x4 __attribute__((ext_vector_type(4)));

// ---------------------------------------------------------------------------
// K1: blocks 0..1023: P[q][n][h][e] = sum of 128 rows of Cp (nontemporal read)
//     blocks 1024..1055: V[d][e] = sum_{j<8} W1[j*64+d][e]
__global__ __launch_bounds__(256) void k_prep(const float* __restrict__ Cp,
                                              const float* __restrict__ W1,
                                              float* __restrict__ P,
                                              float* __restrict__ V) {
    __shared__ f32x4 sh[128];
    int b = blockIdx.x;
    int t = threadIdx.x;
    if (b < 1024) {
        int n   = b >> 5;
        int sub = b & 31;               // 128 rows each
        int h   = sub >> 2;
        int q   = sub & 3;
        int e4  = t & 127;
        int half = t >> 7;
        const f32x4* base = reinterpret_cast<const f32x4*>(Cp) +
            (size_t)(n * LL + sub * 128 + half) * (EE / 4) + e4;
        float ax = 0.f, ay = 0.f, az = 0.f, aw = 0.f;
#pragma unroll 8
        for (int r = 0; r < 64; ++r) {
            f32x4 v = __builtin_nontemporal_load(base + (size_t)r * 2 * (EE / 4));
            ax += v.x; ay += v.y; az += v.z; aw += v.w;
        }
        if (half) { f32x4 o; o.x = ax; o.y = ay; o.z = az; o.w = aw; sh[e4] = o; }
        __syncthreads();
        if (!half) {
            f32x4 o = sh[e4];
            o.x += ax; o.y += ay; o.z += az; o.w += aw;
            reinterpret_cast<f32x4*>(P)[(size_t)((q * NN + n) * HH + h) * 128 + e4] = o;
        }
    } else {
        int idx = (b - 1024) * 256 + t;      // 0..8191 float4 outputs
        int d = idx >> 7, e4 = idx & 127;
        float vx = 0.f, vy = 0.f, vz = 0.f, vw = 0.f;
#pragma unroll
        for (int j = 0; j < 8; ++j) {
            f32x4 v = reinterpret_cast<const f32x4*>(
                W1 + (size_t)(j * 64 + d) * EE)[e4];
            vx += v.x; vy += v.y; vz += v.z; vw += v.w;
        }
        f32x4 o; o.x = vx; o.y = vy; o.z = vz; o.w = vw;
        reinterpret_cast<f32x4*>(V)[(size_t)d * 128 + e4] = o;
    }
}

// ---------------------------------------------------------------------------
// K2: fused phi + w3.  128 blocks = (n, j), j = quarter of the 512 w3 outputs.
//   stage 1: S[h][e] = sum_q P[q][n][h][e]          (16 KB LDS)
//   stage 2: ph[h*64+d] = sum_e S[h][e] * V[d][e]   (2 KB LDS)
//   stage 3: w3[n][j*128 + i] = sum_k ph[k] * W3[j*128+i][k]
__global__ __launch_bounds__(256) void k_phiw3(const float* __restrict__ P,
                                               const float* __restrict__ V,
                                               const float* __restrict__ W3,
                                               float* __restrict__ w3) {
    __shared__ float S[HH * EE];      // 16 KB
    __shared__ float ph[EE];          // 2 KB
    __shared__ float red[256];
    int n = blockIdx.x >> 2;
    int j = blockIdx.x & 3;
    int t = threadIdx.x;

    f32x4* S4 = reinterpret_cast<f32x4*>(S);
    const f32x4* P4 = reinterpret_cast<const f32x4*>(P);
#pragma unroll
    for (int c = 0; c < 4; ++c) {
        int idx = c * 256 + t;        // 0..1023 float4
        f32x4 a = P4[(size_t)(0 * NN + n) * 1024 + idx];
        f32x4 b = P4[(size_t)(1 * NN + n) * 1024 + idx];
        f32x4 d = P4[(size_t)(2 * NN + n) * 1024 + idx];
        f32x4 e = P4[(size_t)(3 * NN + n) * 1024 + idx];
        a.x += b.x + d.x + e.x; a.y += b.y + d.y + e.y;
        a.z += b.z + d.z + e.z; a.w += b.w + d.w + e.w;
        S4[idx] = a;
    }
    __syncthreads();

#pragma unroll
    for (int rep = 0; rep < 2; ++rep) {
        int o = t + rep * 256;
        int h = o >> 6, d = o & 63;
        const f32x4* Vr = reinterpret_cast<const f32x4*>(V) + (size_t)d * 128;
        const f32x4* Sr = reinterpret_cast<const f32x4*>(S) + (size_t)h * 128;
        float acc = 0.f;
#pragma unroll 4
        for (int k = 0; k < 128; ++k) {
            f32x4 s = Sr[k], v = Vr[k];
            acc += s.x * v.x + s.y * v.y + s.z * v.z + s.w * v.w;
        }
        ph[o] = acc;
    }
    __syncthreads();

    int f  = j * 128 + (t >> 1);
    int eh = t & 1;
    const f32x4* Wr = reinterpret_cast<const f32x4*>(W3) + (size_t)f * 128 + eh * 64;
    const f32x4* Pr = reinterpret_cast<const f32x4*>(ph) + eh * 64;
    float acc = 0.f;
#pragma unroll 4
    for (int k = 0; k < 64; ++k) {
        f32x4 p = Pr[k], w = Wr[k];
        acc += p.x * w.x + p.y * w.y + p.z * w.z + p.w * w.w;
    }
    red[t] = acc;
    __syncthreads();
    if (t < 128) w3[(size_t)n * EE + j * 128 + t] = red[2 * t] + red[2 * t + 1];
}

// ---------------------------------------------------------------------------
// Skinny GEMM (R2-proven): out[n][f] = act( A[n][:K] . W[f][:K] (+bias)(+res) )
// MODE: 0 = plain, 1 = relu(s + bias), 2 = s + bias + res
template<int K, int F, int NG, int FPW, int MODE>
__global__ __launch_bounds__(256) void k_gemm(const float* __restrict__ A,
                                              const float* __restrict__ W,
                                              const float* __restrict__ bias,
                                              const float* __restrict__ res,
                                              float* __restrict__ out) {
    constexpr int V4 = K / 256;
    int wid  = (blockIdx.x * 256 + threadIdx.x) >> 6;
    int lane = threadIdx.x & 63;
    constexpr int NGROUPS = NN / NG;
    int ng = wid % NGROUPS;
    int fc = wid / NGROUPS;
    int n0 = ng * NG;
    int f0 = fc * FPW;

    float4 a4[NG][V4];
#pragma unroll
    for (int g = 0; g < NG; ++g)
#pragma unroll
        for (int k = 0; k < V4; ++k)
            a4[g][k] = reinterpret_cast<const float4*>(
                A + (size_t)(n0 + g) * K)[k * 64 + lane];

#pragma unroll
    for (int fi = 0; fi < FPW; ++fi) {
        int f = f0 + fi;
        float4 w4[V4];
#pragma unroll
        for (int k = 0; k < V4; ++k)
            w4[k] = reinterpret_cast<const float4*>(
                W + (size_t)f * K)[k * 64 + lane];
        float acc[NG];
#pragma unroll
        for (int g = 0; g < NG; ++g) {
            float s = 0.f;
#pragma unroll
            for (int k = 0; k < V4; ++k) {
                s += a4[g][k].x * w4[k].x + a4[g][k].y * w4[k].y
                   + a4[g][k].z * w4[k].z + a4[g][k].w * w4[k].w;
            }
#pragma unroll
            for (int m = 32; m > 0; m >>= 1) s += __shfl_xor(s, m);
            acc[g] = s;
        }
        if (lane == 0) {
            float b = (MODE == 0) ? 0.f : bias[f];
#pragma unroll
            for (int g = 0; g < NG; ++g) {
                float v = acc[g] + b;
                if (MODE == 1) v = fmaxf(v, 0.f);
                if (MODE == 2) v += res[(size_t)(n0 + g) * F + f];
                out[(size_t)(n0 + g) * F + f] = v;
            }
        }
    }
}

// ---------------------------------------------------------------------------
// K5: LayerNorm (R2-proven)
__global__ void k_ln(const float* __restrict__ x, const float* __restrict__ gamma,
                     const float* __restrict__ beta, float* __restrict__ out) {
    __shared__ float wred[4];
    int n = blockIdx.x;
    int tid = threadIdx.x;
    float a = x[(size_t)n * EE + tid];
    float b = x[(size_t)n * EE + 256 + tid];
    float s = a + b;
#pragma unroll
    for (int off = 32; off > 0; off >>= 1) s += __shfl_down(s, off);
    int wid = tid >> 6;
    if ((tid & 63) == 0) wred[wid] = s;
    __syncthreads();
    if (tid == 0) wred[0] = (wred[0] + wred[1] + wred[2] + wred[3]) * (1.0f / EE);
    __syncthreads();
    float mu = wred[0];
    float da = a - mu, db = b - mu;
    float q = da * da + db * db;
#pragma unroll
    for (int off = 32; off > 0; off >>= 1) q += __shfl_down(q, off);
    __syncthreads();
    if ((tid & 63) == 0) wred[wid] = q;
    __syncthreads();
    if (tid == 0) wred[0] = (wred[0] + wred[1] + wred[2] + wred[3]) * (1.0f / EE);
    __syncthreads();
    float var = wred[0];
    float rstd = rsqrtf(var + 1e-5f);
    out[(size_t)n * EE + tid]       = da * rstd * gamma[tid] + beta[tid];
    out[(size_t)n * EE + 256 + tid] = db * rstd * gamma[tid + 256] + beta[tid + 256];
}

// ---------------------------------------------------------------------------
extern "C" void kernel_launch(void* const* d_in, const int* in_sizes, int n_in,
                              void* d_out, int out_size, void* d_ws, size_t ws_size,
                              hipStream_t stream) {
    const float* Cp    = (const float*)d_in[0];
    const float* W1    = (const float*)d_in[1];
    // d_in[2] = W2: unused — softmax over a size-1 axis is identically 1.
    const float* W3    = (const float*)d_in[3];
    const float* Wf1   = (const float*)d_in[4];
    const float* bf1   = (const float*)d_in[5];
    const float* Wf2   = (const float*)d_in[6];
    const float* bf2   = (const float*)d_in[7];
    const float* gamma = (const float*)d_in[8];
    const float* beta  = (const float*)d_in[9];
    float* out = (float*)d_out;
    float* ws  = (float*)d_ws;

    float* P  = ws;                         // 4*32*8*512 = 524288 floats (2 MB)
    float* V  = P + (size_t)4 * NN * HH * EE;    // 64*512
    float* w3 = V + (size_t)DD * EE;             // 32*512
    float* h1 = w3 + (size_t)NN * EE;            // 32*2048
    float* x  = h1 + (size_t)NN * FF;            // 32*512

    // K1: Cp row-block partial sums (nontemporal) + W1 colsums
    k_prep<<<1024 + 32, 256, 0, stream>>>(Cp, W1, P, V);
    // K2: fused phi + w3
    k_phiw3<<<NN * 4, 256, 0, stream>>>(P, V, W3, w3);
    // K3: h1 = relu(w3 @ Wf1^T + bf1)
    k_gemm<EE, FF, 8, 2, 1><<<1024, 256, 0, stream>>>(w3, Wf1, bf1, nullptr, h1);
    // K4: x = h1 @ Wf2^T + bf2 + w3
    k_gemm<FF, EE, 4, 1, 2><<<1024, 256, 0, stream>>>(h1, Wf2, bf2, w3, x);
    // K5: LayerNorm
    k_ln<<<NN, 256, 0, stream>>>(x, gamma, beta, out);
}